// Round 7
// baseline (2422.595 us; speedup 1.0000x reference)
//
#include <hip/hip_runtime.h>

#define N_NODES 100000
#define N_EDGES 3200000
#define R_REL   8
#define C_IN    128
#define HID     64
#define WCOLS   576   // 8 relations * 64 + 64 (root slot)

// counting-sort CSR parameters
#define NBUCK 500     // dst buckets
#define NPB   200     // nodes per bucket (500*200 = N)
#define NBLK  1024    // edge chunks
#define CHUNK 3125    // E / NBLK (exact)
#define NCELL (NBUCK * NBLK)   // 512000

typedef __attribute__((ext_vector_type(8))) short  short8;
typedef __attribute__((ext_vector_type(4))) float  float4v;

__device__ __forceinline__ float bf2f(unsigned short u) {
    union { unsigned int i; float f; } v; v.i = ((unsigned int)u) << 16; return v.f;
}
__device__ __forceinline__ unsigned short f2bf(float f) {
    union { float f; unsigned int i; } v; v.f = f;
    unsigned int r = v.i + 0x7FFFu + ((v.i >> 16) & 1u);   // RNE
    return (unsigned short)(r >> 16);
}

// ---------------- weight prep (f32 -> bf16, concatenated+transposed) ----------
__global__ void prep_wcat(const float* __restrict__ W1,
                          const float* __restrict__ root1,
                          const float* __restrict__ W2,
                          const float* __restrict__ root2,
                          unsigned short* __restrict__ BT1,
                          unsigned short* __restrict__ BT2) {
    int idx = blockIdx.x * 256 + threadIdx.x;
    const int T1 = WCOLS * C_IN;          // 73728
    const int T2 = WCOLS * HID;           // 36864
    if (idx < T1) {
        int c = idx / C_IN, k = idx % C_IN;
        float v;
        if (c < 512) { int r = c >> 6, h = c & 63; v = W1[r * (C_IN * 64) + k * 64 + h]; }
        else         { v = root1[k * 64 + (c - 512)]; }
        BT1[idx] = f2bf(v);
    } else if (idx < T1 + T2) {
        int j = idx - T1;
        int c = j / HID, k = j % HID;
        float v;
        if (c < 512) { int r = c >> 6, h = c & 63; v = W2[r * (HID * 64) + k * 64 + h]; }
        else         { v = root2[k * 64 + (c - 512)]; }
        BT2[j] = f2bf(v);
    }
}

// ---------------- K1: per-block LDS counting sort, sequential writes ---------
// esort[blk*CHUNK ...] = block's edges sorted by bucket (packed);
// bcountT[blk*NBUCK+b] = count; lstartT[blk*NBUCK+b] = local exclusive prefix.
__global__ __launch_bounds__(256)
void edge_sort_local(const int* __restrict__ src, const int* __restrict__ dst,
                     const int* __restrict__ et,
                     unsigned int* __restrict__ esort,
                     int* __restrict__ bcountT, int* __restrict__ lstartT) {
    __shared__ int cnt[NBUCK], cur[NBUCK], tsum[256];
    __shared__ unsigned int sedge[CHUNK];
    const int blk = blockIdx.x, tid = threadIdx.x;
    const int e0 = blk * CHUNK;

    for (int i = tid; i < NBUCK; i += 256) cnt[i] = 0;
    __syncthreads();
    for (int i = tid; i < CHUNK; i += 256)
        atomicAdd(&cnt[dst[e0 + i] / NPB], 1);
    __syncthreads();

    // exclusive scan over 500 counters (2 per thread + Hillis-Steele)
    int b0 = tid * 2;
    int s = 0, l1 = 0;
    if (b0 < NBUCK) { s = cnt[b0]; if (b0 + 1 < NBUCK) { l1 = s; s += cnt[b0 + 1]; } }
    tsum[tid] = s; __syncthreads();
    for (int off = 1; off < 256; off <<= 1) {
        int t = (tid >= off) ? tsum[tid - off] : 0;
        __syncthreads(); tsum[tid] += t; __syncthreads();
    }
    int texcl = tsum[tid] - s;
    if (b0 < NBUCK) { cur[b0] = texcl; if (b0 + 1 < NBUCK) cur[b0 + 1] = texcl + l1; }
    __syncthreads();

    for (int b = tid; b < NBUCK; b += 256) {
        bcountT[blk * NBUCK + b] = cnt[b];
        lstartT[blk * NBUCK + b] = cur[b];
    }
    __syncthreads();

    for (int i = tid; i < CHUNK; i += 256) {
        int d = dst[e0 + i];
        int b = d / NPB;
        int pos = atomicAdd(&cur[b], 1);
        sedge[pos] = ((unsigned int)src[e0 + i] << 11) |
                     ((unsigned int)(d - b * NPB) << 3) | (unsigned int)et[e0 + i];
    }
    __syncthreads();
    for (int i = tid; i < CHUNK; i += 256) esort[e0 + i] = sedge[i];
}

// ---------------- scans: exclusive over NCELL, bucket-major ------------------
__global__ __launch_bounds__(1024)
void scan1(const int* __restrict__ bcountT, int* __restrict__ cellstart,
           int* __restrict__ bsum) {
    __shared__ int tmp[1024];
    const int b = blockIdx.x, blk = threadIdx.x;   // one bucket per block
    int v = bcountT[blk * NBUCK + b];
    tmp[blk] = v; __syncthreads();
    for (int off = 1; off < 1024; off <<= 1) {
        int t = (blk >= off) ? tmp[blk - off] : 0;
        __syncthreads(); tmp[blk] += t; __syncthreads();
    }
    cellstart[b * NBLK + blk] = tmp[blk] - v;
    if (blk == 1023) bsum[b] = tmp[blk];
}

__global__ __launch_bounds__(512)
void scan2(int* __restrict__ bsum, int nb) {      // nb <= 512
    __shared__ int tmp[512];
    int tid = threadIdx.x;
    int v = (tid < nb) ? bsum[tid] : 0;
    tmp[tid] = v; __syncthreads();
    for (int off = 1; off < 512; off <<= 1) {
        int t = (tid >= off) ? tmp[tid - off] : 0;
        __syncthreads(); tmp[tid] += t; __syncthreads();
    }
    if (tid < nb) bsum[tid] = tmp[tid] - v;       // exclusive
}

__global__ __launch_bounds__(1024)
void scan3(int* __restrict__ cellstart, const int* __restrict__ bsum) {
    int gid = blockIdx.x * 1024 + threadIdx.x;
    cellstart[gid] += bsum[blockIdx.x];           // grid = NBUCK, bucket-major
}

// ---------------- K4: gather runs -> bucket-major ebucket + wt table ---------
__global__ __launch_bounds__(256)
void edge_move(const unsigned int* __restrict__ esort,
               const int* __restrict__ bcountT, const int* __restrict__ lstartT,
               const int* __restrict__ cellstart,
               unsigned int* __restrict__ ebucket, float* __restrict__ wtab) {
    __shared__ int cnt[NPB * R_REL];              // 1600
    const int b = blockIdx.x, tid = threadIdx.x;
    for (int i = tid; i < NPB * R_REL; i += 256) cnt[i] = 0;
    __syncthreads();
    for (int blk = tid; blk < NBLK; blk += 256) {
        int len = bcountT[blk * NBUCK + b];
        int lp  = blk * CHUNK + lstartT[blk * NBUCK + b];
        int gp  = cellstart[b * NBLK + blk];
        for (int k = 0; k < len; ++k) {
            unsigned int e = esort[lp + k];
            ebucket[gp + k] = e;
            atomicAdd(&cnt[(int)((e >> 3) & 255u) * 8 + (int)(e & 7u)], 1);
        }
    }
    __syncthreads();
    for (int j = tid; j < NPB * R_REL; j += 256) {
        int c = cnt[j];
        wtab[b * (NPB * R_REL) + j] = 1.0f / (float)(c > 1 ? c : 1);
    }
}

// ---------------- GEMM: Out[N][576] (bf16) = A[N][K] @ Wcat ------------------
template <int K, bool AF32>
__global__ __launch_bounds__(256)
void gemm_rows(const void* __restrict__ Araw,
               const unsigned short* __restrict__ BT,
               unsigned short* __restrict__ Out, int nrows) {
    constexpr int KSTEPS = K / 32;
    constexpr int LDB = K + 8;
    __shared__ __align__(16) unsigned short Blds[64 * LDB];
    __shared__ __align__(16) unsigned short stage[4][16 * 64];

    const int wave = threadIdx.x >> 6;
    const int lane = threadIdx.x & 63;
    const int l15 = lane & 15, quad = lane >> 4;
    const int rowbase = blockIdx.x * 64 + wave * 16;
    int arow = rowbase + l15;
    if (arow >= nrows) arow = nrows - 1;

    short8 afrag[KSTEPS];
    if constexpr (AF32) {
        const float* Af = (const float*)Araw;
#pragma unroll
        for (int ks = 0; ks < KSTEPS; ++ks) {
            const float* p = Af + (size_t)arow * K + ks * 32 + quad * 8;
            float4v u0 = *(const float4v*)p;
            float4v u1 = *(const float4v*)(p + 4);
            short8 f;
            f[0] = (short)f2bf(u0[0]); f[1] = (short)f2bf(u0[1]);
            f[2] = (short)f2bf(u0[2]); f[3] = (short)f2bf(u0[3]);
            f[4] = (short)f2bf(u1[0]); f[5] = (short)f2bf(u1[1]);
            f[6] = (short)f2bf(u1[2]); f[7] = (short)f2bf(u1[3]);
            afrag[ks] = f;
        }
    } else {
        const unsigned short* Ab = (const unsigned short*)Araw;
#pragma unroll
        for (int ks = 0; ks < KSTEPS; ++ks)
            afrag[ks] = *(const short8*)(Ab + (size_t)arow * K + ks * 32 + quad * 8);
    }

    for (int chunk = 0; chunk < 9; ++chunk) {
        __syncthreads();
        {
            const unsigned short* src = BT + (size_t)chunk * 64 * K;
            const int nvec = 64 * K / 8;
            for (int i = threadIdx.x; i < nvec; i += 256) {
                int r = i / (K / 8);
                int cpos = (i % (K / 8)) * 8;
                *(uint4*)(&Blds[r * LDB + cpos]) = *(const uint4*)(src + r * K + cpos);
            }
        }
        __syncthreads();

        float4v acc[4];
#pragma unroll
        for (int ct = 0; ct < 4; ++ct) { acc[ct][0] = 0.f; acc[ct][1] = 0.f; acc[ct][2] = 0.f; acc[ct][3] = 0.f; }

#pragma unroll
        for (int ct = 0; ct < 4; ++ct) {
#pragma unroll
            for (int ks = 0; ks < KSTEPS; ++ks) {
                short8 bfrag = *(const short8*)(&Blds[(ct * 16 + l15) * LDB + ks * 32 + quad * 8]);
                acc[ct] = __builtin_amdgcn_mfma_f32_16x16x32_bf16(afrag[ks], bfrag, acc[ct], 0, 0, 0);
            }
        }

#pragma unroll
        for (int ct = 0; ct < 4; ++ct)
#pragma unroll
            for (int r = 0; r < 4; ++r)
                stage[wave][(quad * 4 + r) * 64 + ct * 16 + l15] = f2bf(acc[ct][r]);
        __syncthreads();

        {
            int r = lane >> 2, j = lane & 3;
            int orow = rowbase + r;
            if (orow < nrows) {
#pragma unroll
                for (int p = 0; p < 2; ++p) {
                    int c0 = (j + p * 4) * 8;
                    uint4 v = *(const uint4*)&stage[wave][r * 64 + c0];
                    *(uint4*)(Out + (size_t)orow * WCOLS + chunk * 64 + c0) = v;
                }
            }
        }
    }
}

// ---------------- fused bucket aggregate + root + bias (+relu) ---------------
// one block per bucket; LDS f32 accumulator [NPB][64]; lane = channel.
template <int MODE>   // 0: relu -> bf16 h ; 1: -> f32 out
__global__ __launch_bounds__(256)
void bucket_agg(const unsigned short* __restrict__ XW,
                const unsigned int* __restrict__ ebucket,
                const int* __restrict__ cellstart,
                const float* __restrict__ wtab,
                const float* __restrict__ bias,
                void* __restrict__ outp) {
    __shared__ float acc[NPB * 64];               // 51.2 KB
    __shared__ float wt[NPB * R_REL];             //  6.4 KB
    const int b = blockIdx.x, tid = threadIdx.x;
    const int wave = tid >> 6, lane = tid & 63;

    for (int i = tid; i < NPB * 64; i += 256) acc[i] = 0.f;
    for (int i = tid; i < NPB * R_REL; i += 256) wt[i] = wtab[b * (NPB * R_REL) + i];
    __syncthreads();

    const int seg0 = cellstart[b * NBLK];
    const int seg1 = (b == NBUCK - 1) ? N_EDGES : cellstart[(b + 1) * NBLK];
    const unsigned short* XWl = XW + lane;

    for (int i = seg0 + wave * 64; i < seg1; i += 256) {
        int m = seg1 - i; if (m > 64) m = 64;
        int idx = i + lane; if (idx >= seg1) idx = seg1 - 1;
        unsigned int ub = ebucket[idx];           // 64 edges, one coalesced load

        int j = 0;
        for (; j + 16 <= m; j += 16) {
            float vv[16], ww[16]; int dl[16];
#pragma unroll
            for (int t = 0; t < 16; ++t) {
                unsigned int u = (unsigned int)__builtin_amdgcn_readlane((int)ub, j + t);
                int rel = (int)(u & 7u);
                dl[t] = (int)((u >> 3) & 255u);
                ww[t] = wt[dl[t] * 8 + rel];
                vv[t] = bf2f(XWl[(u >> 11) * WCOLS + rel * 64]);
            }
#pragma unroll
            for (int t = 0; t < 16; ++t)
                atomicAdd(&acc[dl[t] * 64 + lane], ww[t] * vv[t]);
        }
        for (; j < m; ++j) {
            unsigned int u = (unsigned int)__builtin_amdgcn_readlane((int)ub, j);
            int rel = (int)(u & 7u);
            int d = (int)((u >> 3) & 255u);
            atomicAdd(&acc[d * 64 + lane], wt[d * 8 + rel] * bf2f(XWl[(u >> 11) * WCOLS + rel * 64]));
        }
    }
    __syncthreads();

    // epilogue: 200 nodes, fuse root + bias (+relu)
    for (int dl = wave; dl < NPB; dl += 4) {
        int n = b * NPB + dl;
        float res = acc[dl * 64 + lane] + bf2f(XW[(size_t)n * WCOLS + 512 + lane]) + bias[lane];
        if (MODE == 0) {
            res = res > 0.f ? res : 0.f;
            ((unsigned short*)outp)[(size_t)n * 64 + lane] = f2bf(res);
        } else {
            ((float*)outp)[(size_t)n * 64 + lane] = res;
        }
    }
}

// ---------------- launch ------------------------------------------------------
extern "C" void kernel_launch(void* const* d_in, const int* in_sizes, int n_in,
                              void* d_out, int out_size, void* d_ws, size_t ws_size,
                              hipStream_t stream) {
    const float* x     = (const float*)d_in[0];
    const int*   eidx  = (const int*)d_in[1];
    const int*   etyp  = (const int*)d_in[2];
    const float* W1    = (const float*)d_in[3];
    const float* root1 = (const float*)d_in[4];
    const float* b1    = (const float*)d_in[5];
    const float* W2    = (const float*)d_in[6];
    const float* root2 = (const float*)d_in[7];
    const float* b2    = (const float*)d_in[8];
    float*       out   = (float*)d_out;

    char* ws = (char*)d_ws;
    size_t off = 0;
    auto alloc = [&](size_t bytes) { char* p = ws + off; off += (bytes + 255) & ~(size_t)255; return p; };

    unsigned short* xW      = (unsigned short*)alloc((size_t)N_NODES * WCOLS * 2); // 115.2 MB (reused as hW)
    unsigned short* h       = (unsigned short*)alloc((size_t)N_NODES * HID * 2);   //  12.8 MB (aliases esort)
    unsigned int*   ebucket = (unsigned int*)alloc((size_t)N_EDGES * 4);           //  12.8 MB
    int*            bcountT = (int*)alloc((size_t)NCELL * 4);                      //   2.05 MB
    int*            lstartT = (int*)alloc((size_t)NCELL * 4);                      //   2.05 MB
    int*            cellst  = (int*)alloc((size_t)NCELL * 4);                      //   2.05 MB
    int*            bsum    = (int*)alloc(512 * 4);
    float*          wtab    = (float*)alloc((size_t)NBUCK * NPB * R_REL * 4);      //   3.2 MB
    unsigned short* BT1     = (unsigned short*)alloc((size_t)WCOLS * C_IN * 2);
    unsigned short* BT2     = (unsigned short*)alloc((size_t)WCOLS * HID * 2);
    // total ~150.6 MB

    // esort aliases h: esort dead (after edge_move) before h is first written (bucket_agg<0>)
    unsigned int* esort = (unsigned int*)h;       // 12.8 MB = N_EDGES*4 exactly

    const int* srcp = eidx;
    const int* dstp = eidx + N_EDGES;

    prep_wcat<<<(WCOLS * (C_IN + HID) + 255) / 256, 256, 0, stream>>>(W1, root1, W2, root2, BT1, BT2);

    // CSR build — all global writes sequential
    edge_sort_local<<<NBLK, 256, 0, stream>>>(srcp, dstp, etyp, esort, bcountT, lstartT);
    scan1<<<NBUCK, 1024, 0, stream>>>(bcountT, cellst, bsum);
    scan2<<<1, 512, 0, stream>>>(bsum, NBUCK);
    scan3<<<NBUCK, 1024, 0, stream>>>(cellst, bsum);
    edge_move<<<NBUCK, 256, 0, stream>>>(esort, bcountT, lstartT, cellst, ebucket, wtab);

    const int gemm_grid = (N_NODES + 63) / 64;    // 1563

    // layer 1: x (f32) -> xW (bf16) -> h (bf16, relu)
    gemm_rows<C_IN, true><<<gemm_grid, 256, 0, stream>>>((const void*)x, BT1, xW, N_NODES);
    bucket_agg<0><<<NBUCK, 256, 0, stream>>>(xW, ebucket, cellst, wtab, b1, (void*)h);

    // layer 2: h -> hW (reuse xW) -> out (f32)
    gemm_rows<HID, false><<<gemm_grid, 256, 0, stream>>>((const void*)h, BT2, xW, N_NODES);
    bucket_agg<1><<<NBUCK, 256, 0, stream>>>(xW, ebucket, cellst, wtab, b2, (void*)out);
}

// Round 8
// 457.218 us; speedup vs baseline: 5.2986x; 5.2986x over previous
//
#include <hip/hip_runtime.h>

#define N_NODES 100000
#define N_EDGES 3200000
#define R_REL   8
#define C_IN    128
#define HID     64
#define WCOLS   576   // 8 relations * 64 + 64 (root slot)
#define OFFMASK 0x03FFFFFFu

// counting-sort parameters
#define NBUCK 500     // dst buckets
#define NPB   200     // nodes per bucket (500*200 = N)
#define NBLK  1024    // edge chunks
#define CHUNK 3125    // E / NBLK (exact)
#define NCELL (NBUCK * NBLK)   // 512000

typedef __attribute__((ext_vector_type(8))) short  short8;
typedef __attribute__((ext_vector_type(4))) float  float4v;

__device__ __forceinline__ float bf2f(unsigned short u) {
    union { unsigned int i; float f; } v; v.i = ((unsigned int)u) << 16; return v.f;
}
__device__ __forceinline__ unsigned short f2bf(float f) {
    union { float f; unsigned int i; } v; v.f = f;
    unsigned int r = v.i + 0x7FFFu + ((v.i >> 16) & 1u);   // RNE
    return (unsigned short)(r >> 16);
}
__device__ __forceinline__ float rl_f(float v, int j) {
    union { float f; int i; } a, b; a.f = v;
    b.i = __builtin_amdgcn_readlane(a.i, j);
    return b.f;
}

// ---------------- weight prep (f32 -> bf16, concatenated+transposed) ----------
__global__ void prep_wcat(const float* __restrict__ W1,
                          const float* __restrict__ root1,
                          const float* __restrict__ W2,
                          const float* __restrict__ root2,
                          unsigned short* __restrict__ BT1,
                          unsigned short* __restrict__ BT2) {
    int idx = blockIdx.x * 256 + threadIdx.x;
    const int T1 = WCOLS * C_IN;          // 73728
    const int T2 = WCOLS * HID;           // 36864
    if (idx < T1) {
        int c = idx / C_IN, k = idx % C_IN;
        float v;
        if (c < 512) { int r = c >> 6, h = c & 63; v = W1[r * (C_IN * 64) + k * 64 + h]; }
        else         { v = root1[k * 64 + (c - 512)]; }
        BT1[idx] = f2bf(v);
    } else if (idx < T1 + T2) {
        int j = idx - T1;
        int c = j / HID, k = j % HID;
        float v;
        if (c < 512) { int r = c >> 6, h = c & 63; v = W2[r * (HID * 64) + k * 64 + h]; }
        else         { v = root2[k * 64 + (c - 512)]; }
        BT2[j] = f2bf(v);
    }
}

// ---------------- K1: per-block LDS counting sort, sequential writes ---------
// esort[blk*CHUNK...] = block's edges sorted by bucket (packed src<<11|dl<<3|rel)
// bcountT[blk*NBUCK+b] = count; lstartT[blk*NBUCK+b] = local exclusive prefix.
__global__ __launch_bounds__(256)
void edge_sort_local(const int* __restrict__ src, const int* __restrict__ dst,
                     const int* __restrict__ et,
                     unsigned int* __restrict__ esort,
                     int* __restrict__ bcountT, int* __restrict__ lstartT) {
    __shared__ int cnt[NBUCK], cur[NBUCK], tsum[256];
    __shared__ unsigned int sedge[CHUNK];
    const int blk = blockIdx.x, tid = threadIdx.x;
    const int e0 = blk * CHUNK;

    for (int i = tid; i < NBUCK; i += 256) cnt[i] = 0;
    __syncthreads();
    for (int i = tid; i < CHUNK; i += 256)
        atomicAdd(&cnt[dst[e0 + i] / NPB], 1);
    __syncthreads();

    // exclusive scan over 500 counters (2 per thread + Hillis-Steele)
    int b0 = tid * 2;
    int s = 0, l1 = 0;
    if (b0 < NBUCK) { s = cnt[b0]; if (b0 + 1 < NBUCK) { l1 = s; s += cnt[b0 + 1]; } }
    tsum[tid] = s; __syncthreads();
    for (int off = 1; off < 256; off <<= 1) {
        int t = (tid >= off) ? tsum[tid - off] : 0;
        __syncthreads(); tsum[tid] += t; __syncthreads();
    }
    int texcl = tsum[tid] - s;
    if (b0 < NBUCK) { cur[b0] = texcl; if (b0 + 1 < NBUCK) cur[b0 + 1] = texcl + l1; }
    __syncthreads();

    for (int b = tid; b < NBUCK; b += 256) {
        bcountT[blk * NBUCK + b] = cnt[b];
        lstartT[blk * NBUCK + b] = cur[b];
    }
    __syncthreads();

    for (int i = tid; i < CHUNK; i += 256) {
        int d = dst[e0 + i];
        int b = d / NPB;
        int pos = atomicAdd(&cur[b], 1);
        sedge[pos] = ((unsigned int)src[e0 + i] << 11) |
                     ((unsigned int)(d - b * NPB) << 3) | (unsigned int)et[e0 + i];
    }
    __syncthreads();
    for (int i = tid; i < CHUNK; i += 256) esort[e0 + i] = sedge[i];
}

// ---------------- bucket totals + scan over 500 buckets ----------------------
__global__ __launch_bounds__(256)
void btot_sum(const int* __restrict__ bcountT, int* __restrict__ btot) {
    __shared__ int tsum[256];
    const int b = blockIdx.x, tid = threadIdx.x;
    int s = 0;
    for (int blk = tid; blk < NBLK; blk += 256) s += bcountT[blk * NBUCK + b];
    tsum[tid] = s; __syncthreads();
    for (int off = 128; off > 0; off >>= 1) {
        if (tid < off) tsum[tid] += tsum[tid + off];
        __syncthreads();
    }
    if (tid == 0) btot[b] = tsum[0];
}

__global__ __launch_bounds__(512)
void scan_btot(int* __restrict__ btot, int nb) {   // nb <= 512, exclusive in place
    __shared__ int tmp[512];
    int tid = threadIdx.x;
    int v = (tid < nb) ? btot[tid] : 0;
    tmp[tid] = v; __syncthreads();
    for (int off = 1; off < 512; off <<= 1) {
        int t = (tid >= off) ? tmp[tid - off] : 0;
        __syncthreads(); tmp[tid] += t; __syncthreads();
    }
    if (tid < nb) btot[tid] = tmp[tid] - v;
}

// ---------------- bucket_build: runs -> CSR (elist, welist, rowstart) --------
// one block per bucket; reads per-block runs from esort; 2 passes
__global__ __launch_bounds__(256)
void bucket_build(const unsigned int* __restrict__ esort,
                  const int* __restrict__ bcountT, const int* __restrict__ lstartT,
                  const int* __restrict__ btot,
                  unsigned int* __restrict__ elist, float* __restrict__ welist,
                  int* __restrict__ rowstart) {
    __shared__ int   cnt[1792], cur[1792], tsum[256];   // (dl*8+rel), padded 256*7
    __shared__ float wt[1600];
    __shared__ int   rlen[NBLK], rpos[NBLK];            // run info, 8 KB
    const int b = blockIdx.x, tid = threadIdx.x;
    const int seg0 = btot[b];

    for (int i = tid; i < 1792; i += 256) cnt[i] = 0;
    for (int blk = tid; blk < NBLK; blk += 256) {
        rlen[blk] = bcountT[blk * NBUCK + b];
        rpos[blk] = blk * CHUNK + lstartT[blk * NBUCK + b];
    }
    __syncthreads();

    // pass 1: histogram (dstLocal, rel)
    for (int blk = tid; blk < NBLK; blk += 256) {
        int len = rlen[blk], lp = rpos[blk];
        for (int k = 0; k < len; ++k) {
            unsigned int e = esort[lp + k];
            atomicAdd(&cnt[(int)((e >> 3) & 255u) * 8 + (int)(e & 7u)], 1);
        }
    }
    __syncthreads();

    // exclusive scan over 1792 counters: 7/thread + Hillis-Steele over 256
    int base = tid * 7, s = 0, loc[7];
#pragma unroll
    for (int k = 0; k < 7; ++k) { loc[k] = s; s += cnt[base + k]; }
    tsum[tid] = s; __syncthreads();
    for (int off = 1; off < 256; off <<= 1) {
        int t = (tid >= off) ? tsum[tid - off] : 0;
        __syncthreads(); tsum[tid] += t; __syncthreads();
    }
    int texcl = tsum[tid] - s;
#pragma unroll
    for (int k = 0; k < 7; ++k) cur[base + k] = texcl + loc[k];
    __syncthreads();

    for (int j = tid; j < 1600; j += 256) {
        int c = cnt[j];
        wt[j] = 1.0f / (float)(c > 1 ? c : 1);
    }
    if (tid < NPB) rowstart[b * NPB + tid] = seg0 + cur[tid * 8];
    if (b == NBUCK - 1 && tid == 0) rowstart[N_NODES] = N_EDGES;
    __syncthreads();

    // pass 2: emit precomputed XW offsets + per-edge weights
    for (int blk = tid; blk < NBLK; blk += 256) {
        int len = rlen[blk], lp = rpos[blk];
        for (int k = 0; k < len; ++k) {
            unsigned int e = esort[lp + k];
            int r = (int)(e & 7u);
            int j = (int)((e >> 3) & 255u) * 8 + r;
            int p = atomicAdd(&cur[j], 1);
            elist[seg0 + p]  = (e >> 11) * WCOLS + (unsigned int)(r * 64);
            welist[seg0 + p] = wt[j];
        }
    }
}

// ---------------- GEMM: Out[N][576] (bf16) = A[N][K] @ Wcat ------------------
template <int K, bool AF32>
__global__ __launch_bounds__(256)
void gemm_rows(const void* __restrict__ Araw,
               const unsigned short* __restrict__ BT,
               unsigned short* __restrict__ Out, int nrows) {
    constexpr int KSTEPS = K / 32;
    constexpr int LDB = K + 8;
    __shared__ __align__(16) unsigned short Blds[64 * LDB];
    __shared__ __align__(16) unsigned short stage[4][16 * 64];

    const int wave = threadIdx.x >> 6;
    const int lane = threadIdx.x & 63;
    const int l15 = lane & 15, quad = lane >> 4;
    const int rowbase = blockIdx.x * 64 + wave * 16;
    int arow = rowbase + l15;
    if (arow >= nrows) arow = nrows - 1;

    short8 afrag[KSTEPS];
    if constexpr (AF32) {
        const float* Af = (const float*)Araw;
#pragma unroll
        for (int ks = 0; ks < KSTEPS; ++ks) {
            const float* p = Af + (size_t)arow * K + ks * 32 + quad * 8;
            float4v u0 = *(const float4v*)p;
            float4v u1 = *(const float4v*)(p + 4);
            short8 f;
            f[0] = (short)f2bf(u0[0]); f[1] = (short)f2bf(u0[1]);
            f[2] = (short)f2bf(u0[2]); f[3] = (short)f2bf(u0[3]);
            f[4] = (short)f2bf(u1[0]); f[5] = (short)f2bf(u1[1]);
            f[6] = (short)f2bf(u1[2]); f[7] = (short)f2bf(u1[3]);
            afrag[ks] = f;
        }
    } else {
        const unsigned short* Ab = (const unsigned short*)Araw;
#pragma unroll
        for (int ks = 0; ks < KSTEPS; ++ks)
            afrag[ks] = *(const short8*)(Ab + (size_t)arow * K + ks * 32 + quad * 8);
    }

    for (int chunk = 0; chunk < 9; ++chunk) {
        __syncthreads();
        {
            const unsigned short* src = BT + (size_t)chunk * 64 * K;
            const int nvec = 64 * K / 8;
            for (int i = threadIdx.x; i < nvec; i += 256) {
                int r = i / (K / 8);
                int cpos = (i % (K / 8)) * 8;
                *(uint4*)(&Blds[r * LDB + cpos]) = *(const uint4*)(src + r * K + cpos);
            }
        }
        __syncthreads();

        float4v acc[4];
#pragma unroll
        for (int ct = 0; ct < 4; ++ct) { acc[ct][0] = 0.f; acc[ct][1] = 0.f; acc[ct][2] = 0.f; acc[ct][3] = 0.f; }

#pragma unroll
        for (int ct = 0; ct < 4; ++ct) {
#pragma unroll
            for (int ks = 0; ks < KSTEPS; ++ks) {
                short8 bfrag = *(const short8*)(&Blds[(ct * 16 + l15) * LDB + ks * 32 + quad * 8]);
                acc[ct] = __builtin_amdgcn_mfma_f32_16x16x32_bf16(afrag[ks], bfrag, acc[ct], 0, 0, 0);
            }
        }

#pragma unroll
        for (int ct = 0; ct < 4; ++ct)
#pragma unroll
            for (int r = 0; r < 4; ++r)
                stage[wave][(quad * 4 + r) * 64 + ct * 16 + l15] = f2bf(acc[ct][r]);
        __syncthreads();

        {
            int r = lane >> 2, j = lane & 3;
            int orow = rowbase + r;
            if (orow < nrows) {
#pragma unroll
                for (int p = 0; p < 2; ++p) {
                    int c0 = (j + p * 4) * 8;
                    uint4 v = *(const uint4*)&stage[wave][r * 64 + c0];
                    *(uint4*)(Out + (size_t)orow * WCOLS + chunk * 64 + c0) = v;
                }
            }
        }
    }
}

// ---------------- fused CSR aggregate + root + bias (+relu) ------------------
// one wave per node, lane = channel. 16-deep explicit gather pipeline.
template <int MODE>   // 0: relu -> bf16 h ; 1: -> f32 out
__global__ __launch_bounds__(256)
void agg_fused(const unsigned short* __restrict__ XW,
               const unsigned int* __restrict__ elist,
               const float* __restrict__ welist,
               const int* __restrict__ rowstart,
               const float* __restrict__ bias,
               void* __restrict__ outp) {
    const int wave = threadIdx.x >> 6, lane = threadIdx.x & 63;
    const int n = blockIdx.x * 4 + wave;          // grid covers N exactly
    const int beg = rowstart[n], end = rowstart[n + 1];

    const unsigned short* XWl = XW + lane;        // fold lane offset into base

    float acc = 0.f;
    int i = beg;
    while (i < end) {
        int m = end - i; if (m > 64) m = 64;
        int idx = i + lane; if (idx >= end) idx = end - 1;
        unsigned int ub = elist[idx];             // one coalesced load / 64 edges
        float        wb = welist[idx];

        int j = 0;
        for (; j + 16 <= m; j += 16) {
            float vv[16], ww[16];
#pragma unroll
            for (int t = 0; t < 16; ++t) {
                unsigned int u = (unsigned int)__builtin_amdgcn_readlane((int)ub, j + t) & OFFMASK;
                ww[t] = rl_f(wb, j + t);
                vv[t] = bf2f(XWl[u]);
            }
#pragma unroll
            for (int t = 0; t < 16; ++t) acc += ww[t] * vv[t];
        }
        for (; j + 4 <= m; j += 4) {
            float vv[4], ww[4];
#pragma unroll
            for (int t = 0; t < 4; ++t) {
                unsigned int u = (unsigned int)__builtin_amdgcn_readlane((int)ub, j + t) & OFFMASK;
                ww[t] = rl_f(wb, j + t);
                vv[t] = bf2f(XWl[u]);
            }
#pragma unroll
            for (int t = 0; t < 4; ++t) acc += ww[t] * vv[t];
        }
        for (; j < m; ++j) {
            unsigned int u = (unsigned int)__builtin_amdgcn_readlane((int)ub, j) & OFFMASK;
            float w = rl_f(wb, j);
            acc += w * bf2f(XWl[u]);
        }
        i += m;
    }

    float res = acc + bf2f(XW[(size_t)n * WCOLS + 512 + lane]) + bias[lane];
    if (MODE == 0) {
        res = res > 0.f ? res : 0.f;
        ((unsigned short*)outp)[(size_t)n * 64 + lane] = f2bf(res);
    } else {
        ((float*)outp)[(size_t)n * 64 + lane] = res;
    }
}

// ---------------- launch ------------------------------------------------------
extern "C" void kernel_launch(void* const* d_in, const int* in_sizes, int n_in,
                              void* d_out, int out_size, void* d_ws, size_t ws_size,
                              hipStream_t stream) {
    const float* x     = (const float*)d_in[0];
    const int*   eidx  = (const int*)d_in[1];
    const int*   etyp  = (const int*)d_in[2];
    const float* W1    = (const float*)d_in[3];
    const float* root1 = (const float*)d_in[4];
    const float* b1    = (const float*)d_in[5];
    const float* W2    = (const float*)d_in[6];
    const float* root2 = (const float*)d_in[7];
    const float* b2    = (const float*)d_in[8];
    float*       out   = (float*)d_out;

    char* ws = (char*)d_ws;
    size_t off = 0;
    auto alloc = [&](size_t bytes) { char* p = ws + off; off += (bytes + 255) & ~(size_t)255; return p; };

    unsigned short* xW       = (unsigned short*)alloc((size_t)N_NODES * WCOLS * 2); // 115.2 MB (reused as hW)
    unsigned short* h        = (unsigned short*)alloc((size_t)N_NODES * HID * 2);   //  12.8 MB
    unsigned int*   elist    = (unsigned int*)alloc((size_t)N_EDGES * 4);           //  12.8 MB
    float*          welist   = (float*)alloc((size_t)N_EDGES * 4);                  //  12.8 MB
    int*            rowstart = (int*)alloc((size_t)(N_NODES + 1) * 4);              //   0.4 MB
    unsigned short* BT1      = (unsigned short*)alloc((size_t)WCOLS * C_IN * 2);
    unsigned short* BT2      = (unsigned short*)alloc((size_t)WCOLS * HID * 2);
    // total ~154.4 MB

    // sort scratch aliases into xW (dead before gemm1 writes xW)
    unsigned int* esort   = (unsigned int*)xW;                          // 12.8 MB
    int*          bcountT = (int*)((char*)xW + (size_t)N_EDGES * 4);    //  2.05 MB
    int*          lstartT = bcountT + NCELL;                            //  2.05 MB
    int*          btot    = lstartT + NCELL;                            //  2 KB

    const int* srcp = eidx;
    const int* dstp = eidx + N_EDGES;

    prep_wcat<<<(WCOLS * (C_IN + HID) + 255) / 256, 256, 0, stream>>>(W1, root1, W2, root2, BT1, BT2);

    // CSR build — sequential-write sort + fused per-bucket CSR emit
    edge_sort_local<<<NBLK, 256, 0, stream>>>(srcp, dstp, etyp, esort, bcountT, lstartT);
    btot_sum<<<NBUCK, 256, 0, stream>>>(bcountT, btot);
    scan_btot<<<1, 512, 0, stream>>>(btot, NBUCK);
    bucket_build<<<NBUCK, 256, 0, stream>>>(esort, bcountT, lstartT, btot, elist, welist, rowstart);

    const int gemm_grid = (N_NODES + 63) / 64;    // 1563
    const int agg_grid  = N_NODES / 4;            // 25000

    // layer 1: x (f32) -> xW (bf16) -> h (bf16, relu)
    gemm_rows<C_IN, true><<<gemm_grid, 256, 0, stream>>>((const void*)x, BT1, xW, N_NODES);
    agg_fused<0><<<agg_grid, 256, 0, stream>>>(xW, elist, welist, rowstart, b1, (void*)h);

    // layer 2: h -> hW (reuse xW) -> out (f32)
    gemm_rows<HID, false><<<gemm_grid, 256, 0, stream>>>((const void*)h, BT2, xW, N_NODES);
    agg_fused<1><<<agg_grid, 256, 0, stream>>>(xW, elist, welist, rowstart, b2, (void*)out);
}